// Round 2
// baseline (480.660 us; speedup 1.0000x reference)
//
#include <hip/hip_runtime.h>
#include <hip/hip_bf16.h>
#include <cstdint>
#include <cstddef>

#define NB 8
#define CIN 256
#define HWX 4096
#define CF 256
#define CA 128
#define CT 384

typedef __attribute__((ext_vector_type(8))) short short8;
typedef __attribute__((ext_vector_type(4))) float f32x4;
typedef __attribute__((ext_vector_type(4))) unsigned int u32x4;

// workspace layout (bytes)
#define OFF_W    0                              // 384*256 fp32 folded weights
#define OFF_BIAS (CT*CIN*4)                     // 384 fp32 folded bias
#define OFF_FEAT (OFF_BIAS + 2048)              // [n][256][4096] bf16
#define OFF_QHI  (OFF_FEAT + NB*CF*HWX*2)       // [n][4096][128] bf16 (hi part)
#define OFF_QLO  (OFF_QHI + NB*HWX*CA*2)       // [n][4096][128] bf16 (lo part)

__device__ inline unsigned short bf16_bits(float f) {
  __hip_bfloat16 h = __float2bfloat16(f);
  return __builtin_bit_cast(unsigned short, h);
}
__device__ inline float bf16_to_f(unsigned short u) {
  __hip_bfloat16 h = __builtin_bit_cast(__hip_bfloat16, u);
  return __bfloat162float(h);
}

// async global->LDS, 16B per lane. LDS side is wave-uniform base + lane*16,
// so callers must arrange lane-linear LDS layout (swizzle goes on the global side).
__device__ inline void g2l16(const void* g, void* l) {
  __builtin_amdgcn_global_load_lds(
      (const __attribute__((address_space(1))) unsigned int*)g,
      (__attribute__((address_space(3))) unsigned int*)l, 16, 0, 0);
}

// ---------------- kernel 1: fold BN into weights ----------------
__global__ __launch_bounds__(256) void fold_bn_k(
    const float* __restrict__ rw, const float* __restrict__ rg,
    const float* __restrict__ rb, const float* __restrict__ rm, const float* __restrict__ rv,
    const float* __restrict__ aw, const float* __restrict__ ag,
    const float* __restrict__ ab2, const float* __restrict__ am, const float* __restrict__ av,
    float* __restrict__ wf, float* __restrict__ bias) {
  int o = blockIdx.x, k = threadIdx.x;
  const float* wsrc; float g, b, m, v;
  if (o < CF) { wsrc = rw + (size_t)o*CIN; g = rg[o]; b = rb[o]; m = rm[o]; v = rv[o]; }
  else { int oa = o - CF; wsrc = aw + (size_t)oa*CIN; g = ag[oa]; b = ab2[oa]; m = am[oa]; v = av[oa]; }
  float inv = g / sqrtf(v + 1e-5f);
  wf[(size_t)o*CIN + k] = wsrc[k] * inv;
  if (k == 0) bias[o] = b - m*inv;
}

// ---------------- kernel 2: fp32 conv(1x1)+BN+ReLU GEMM ----------------
// grid 768 = 8n * 3 och-tiles(128) * 32 pos-tiles(128); 256 thr, 8x8 per thread
__global__ __launch_bounds__(256) void conv_k(
    const float* __restrict__ x, const float* __restrict__ wf,
    const float* __restrict__ bias, unsigned short* __restrict__ feat,
    unsigned short* __restrict__ qhi, unsigned short* __restrict__ qlo) {
  __shared__ float w_s[16][132];   // [k][oc], padded
  __shared__ float x_s[16][132];   // [k][pos], padded
  int b = blockIdx.x;
  int n = b / 96, rem = b % 96;
  int ot = rem / 32, pt = rem % 32;
  int oc0 = ot*128, p0 = pt*128;
  int t = threadIdx.x, ty = t >> 4, tx = t & 15;
  const float* xn = x + (size_t)n*CIN*HWX;
  float acc[8][8];
  #pragma unroll
  for (int i=0;i<8;i++)
    #pragma unroll
    for (int j=0;j<8;j++) acc[i][j]=0.f;

  for (int k0=0; k0<CIN; k0+=16) {
    __syncthreads();
    #pragma unroll
    for (int pass=0; pass<2; pass++) {
      int idx = pass*256+t, oc = idx>>2, kq = idx&3;
      f32x4 wv = *(const f32x4*)(wf + (size_t)(oc0+oc)*CIN + k0 + kq*4);
      w_s[kq*4+0][oc]=wv.x; w_s[kq*4+1][oc]=wv.y; w_s[kq*4+2][oc]=wv.z; w_s[kq*4+3][oc]=wv.w;
    }
    #pragma unroll
    for (int pass=0; pass<2; pass++) {
      int idx = pass*256+t, row = idx>>5, cc = idx&31;
      f32x4 xv = *(const f32x4*)(xn + (size_t)(k0+row)*HWX + p0 + cc*4);
      *(f32x4*)&x_s[row][cc*4] = xv;
    }
    __syncthreads();
    #pragma unroll
    for (int kk=0; kk<16; kk++) {
      float a[8], bb[8];
      *(f32x4*)&a[0]  = *(const f32x4*)&w_s[kk][ty*8];
      *(f32x4*)&a[4]  = *(const f32x4*)&w_s[kk][ty*8+4];
      *(f32x4*)&bb[0] = *(const f32x4*)&x_s[kk][tx*8];
      *(f32x4*)&bb[4] = *(const f32x4*)&x_s[kk][tx*8+4];
      #pragma unroll
      for (int i=0;i<8;i++)
        #pragma unroll
        for (int j=0;j<8;j++) acc[i][j] = fmaf(a[i], bb[j], acc[i][j]);
    }
  }

  int posb = p0 + tx*8;
  float bs[8];
  #pragma unroll
  for (int i=0;i<8;i++) bs[i] = bias[oc0 + ty*8 + i];

  if (oc0 < CF) {
    // feat path: [n][c][pos] bf16
    #pragma unroll
    for (int i=0;i<8;i++) {
      int oc = oc0 + ty*8 + i;
      alignas(16) unsigned short u[8];
      #pragma unroll
      for (int j=0;j<8;j++) {
        float vv = fmaxf(acc[i][j] + bs[i], 0.f);
        u[j] = bf16_bits(vv);
      }
      *(u32x4*)(feat + (size_t)n*CF*HWX + (size_t)oc*HWX + posb) = *(const u32x4*)u;
    }
  } else {
    // q path: [n][pos][c] bf16 hi/lo split (fp32-accurate energy later)
    int cb = oc0 - CF + ty*8;
    #pragma unroll
    for (int j=0;j<8;j++) {
      alignas(16) unsigned short uh[8], ul[8];
      #pragma unroll
      for (int i=0;i<8;i++) {
        float vv = fmaxf(acc[i][j] + bs[i], 0.f);
        unsigned short h = bf16_bits(vv);
        uh[i] = h;
        ul[i] = bf16_bits(vv - bf16_to_f(h));
      }
      size_t base = ((size_t)n*HWX + posb + j)*CA + cb;
      *(u32x4*)(qhi + base) = *(const u32x4*)uh;
      *(u32x4*)(qlo + base) = *(const u32x4*)ul;
    }
  }
}

// ---------------- kernel 3: flash attention, BM=128 ----------------
// grid 256: n = bid&7 (XCD affinity), it = bid>>3; 4 waves x 32 i-rows (2 groups of 16)
// Double-buffered j-tiles (LDS ~150KB, 1 block/CU); each LDS B-frag read feeds 2x MFMAs.
__global__ __launch_bounds__(256, 1) void flash_k(
    const unsigned short* __restrict__ qhi, const unsigned short* __restrict__ qlo,
    const unsigned short* __restrict__ feat, const float* __restrict__ mask,
    float* __restrict__ out) {
  __shared__ alignas(16) unsigned short sQh[2][64*128];  // j-tile q hi, octet-swizzled rows
  __shared__ alignas(16) unsigned short sQl[2][64*128];
  __shared__ alignas(16) unsigned short sF[2][256*64];   // feat tile [c][j], octet-swizzled
  __shared__ alignas(16) unsigned short sP[4][32][72];   // per-wave P (2 groups), stride 72
  __shared__ float sM[2][64];
  int b = blockIdx.x;
  int n = b & 7, it = b >> 3;
  int i0 = it * 128;
  int t = threadIdx.x;
  int w = t >> 6, lane = t & 63, quad = lane >> 4, col = lane & 15;
  const unsigned short* qh_n = qhi + (size_t)n*HWX*CA;
  const unsigned short* ql_n = qlo + (size_t)n*HWX*CA;
  const unsigned short* f_n  = feat + (size_t)n*CF*HWX;
  const float* m_n = mask + (size_t)n*HWX;

  // preload A fragments (q rows of this wave's 2x16 i's), constant over j-loop
  short8 ah[2][4], al[2][4];
  #pragma unroll
  for (int g=0; g<2; g++) {
    int arow = i0 + w*32 + g*16 + col;
    #pragma unroll
    for (int ks=0; ks<4; ks++) {
      ah[g][ks] = *(const short8*)(qh_n + (size_t)arow*CA + ks*32 + quad*8);
      al[g][ks] = *(const short8*)(ql_n + (size_t)arow*CA + ks*32 + quad*8);
    }
  }
  f32x4 fzero = {0.f,0.f,0.f,0.f};
  f32x4 o[2][16];
  #pragma unroll
  for (int g=0;g<2;g++)
    #pragma unroll
    for (int i=0;i<16;i++) o[g][i] = fzero;
  float mrun[2][4], lrun[2][4];
  #pragma unroll
  for (int g=0;g<2;g++)
    #pragma unroll
    for (int r=0;r<4;r++){ mrun[g][r] = -INFINITY; lrun[g][r] = 0.f; }
  const float inv_s = 1.0f/(1e-8f + sqrtf(128.0f));
  const int rloc = t >> 4, oct16 = t & 15;
  const int frow = t >> 3, oct8 = t & 7;

  // stage j-tile jt into buffer buf (async; completes at next __syncthreads)
  auto stage = [&](int j0, int buf) {
    #pragma unroll
    for (int c=0;c<4;c++) {
      int row = c*16 + rloc;
      int og = oct16 ^ (row & 15);
      g2l16(qh_n + (size_t)(j0+row)*CA + og*8, &sQh[buf][(size_t)row*128 + oct16*8]);
    }
    #pragma unroll
    for (int c=0;c<4;c++) {
      int row = c*16 + rloc;
      int og = oct16 ^ (row & 15);
      g2l16(ql_n + (size_t)(j0+row)*CA + og*8, &sQl[buf][(size_t)row*128 + oct16*8]);
    }
    #pragma unroll
    for (int p=0;p<8;p++) {
      int row = p*32 + frow;
      int og = oct8 ^ (row & 7);
      g2l16(f_n + (size_t)row*HWX + j0 + og*8, &sF[buf][(size_t)row*64 + oct8*8]);
    }
    if (t < 16) g2l16(m_n + j0 + t*4, &sM[buf][t*4]);
  };

  stage(0, 0);

  for (int ji = 0; ji < 64; ji++) {
    int buf = ji & 1;
    __syncthreads();               // drains vmcnt: stage(ji) complete for all waves
    if (ji + 1 < 64) stage((ji+1)*64, buf ^ 1);  // prefetch overlaps compute below

    // ---- QK^T: S[2 groups x 16 i x 64 j] per wave, split precision (hh+lh+hl)
    f32x4 s[2][4];
    #pragma unroll
    for (int g=0;g<2;g++)
      #pragma unroll
      for (int jt=0;jt<4;jt++) s[g][jt] = fzero;
    #pragma unroll
    for (int jt=0;jt<4;jt++) {
      int row = jt*16 + col;
      #pragma unroll
      for (int ks=0; ks<4; ks++) {
        int slot = (ks*4 + quad) ^ (row & 15);
        short8 bh = *(const short8*)&sQh[buf][row*128 + slot*8];
        short8 bl = *(const short8*)&sQl[buf][row*128 + slot*8];
        s[0][jt] = __builtin_amdgcn_mfma_f32_16x16x32_bf16(ah[0][ks], bh, s[0][jt], 0, 0, 0);
        s[1][jt] = __builtin_amdgcn_mfma_f32_16x16x32_bf16(ah[1][ks], bh, s[1][jt], 0, 0, 0);
        s[0][jt] = __builtin_amdgcn_mfma_f32_16x16x32_bf16(al[0][ks], bh, s[0][jt], 0, 0, 0);
        s[1][jt] = __builtin_amdgcn_mfma_f32_16x16x32_bf16(al[1][ks], bh, s[1][jt], 0, 0, 0);
        s[0][jt] = __builtin_amdgcn_mfma_f32_16x16x32_bf16(ah[0][ks], bl, s[0][jt], 0, 0, 0);
        s[1][jt] = __builtin_amdgcn_mfma_f32_16x16x32_bf16(ah[1][ks], bl, s[1][jt], 0, 0, 0);
      }
    }

    // ---- online softmax; C/D layout: row = quad*4+r (i), col = lane&15 (j)
    float mj[4];
    #pragma unroll
    for (int jt=0;jt<4;jt++) mj[jt] = (sM[buf][jt*16+col] - 1.f) * 1e8f;
    float sv[2][4][4], alpha[2][4];
    #pragma unroll
    for (int g=0;g<2;g++)
      #pragma unroll
      for (int jt=0;jt<4;jt++)
        #pragma unroll
        for (int r=0;r<4;r++) sv[g][jt][r] = s[g][jt][r]*inv_s + mj[jt];
    #pragma unroll
    for (int g=0;g<2;g++) {
      #pragma unroll
      for (int r=0;r<4;r++) {
        float mx = fmaxf(fmaxf(sv[g][0][r],sv[g][1][r]), fmaxf(sv[g][2][r],sv[g][3][r]));
        mx = fmaxf(mx, __shfl_xor(mx, 1, 64));
        mx = fmaxf(mx, __shfl_xor(mx, 2, 64));
        mx = fmaxf(mx, __shfl_xor(mx, 4, 64));
        mx = fmaxf(mx, __shfl_xor(mx, 8, 64));
        float mn = fmaxf(mrun[g][r], mx);
        alpha[g][r] = __expf(mrun[g][r] - mn);
        mrun[g][r] = mn;
        float ss = 0.f;
        #pragma unroll
        for (int jt=0;jt<4;jt++) { float p = __expf(sv[g][jt][r] - mn); sv[g][jt][r] = p; ss += p; }
        ss += __shfl_xor(ss, 1, 64);
        ss += __shfl_xor(ss, 2, 64);
        ss += __shfl_xor(ss, 4, 64);
        ss += __shfl_xor(ss, 8, 64);
        lrun[g][r] = lrun[g][r]*alpha[g][r] + ss;
      }
      bool need = (alpha[g][0]!=1.f)|(alpha[g][1]!=1.f)|(alpha[g][2]!=1.f)|(alpha[g][3]!=1.f);
      if (__ballot(need)) {
        #pragma unroll
        for (int ct=0;ct<16;ct++) {
          o[g][ct][0]*=alpha[g][0]; o[g][ct][1]*=alpha[g][1];
          o[g][ct][2]*=alpha[g][2]; o[g][ct][3]*=alpha[g][3];
        }
      }
    }

    // ---- P: C/D layout -> A-operand layout via per-wave LDS buffer (both groups)
    #pragma unroll
    for (int g=0;g<2;g++)
      #pragma unroll
      for (int jt=0;jt<4;jt++)
        #pragma unroll
        for (int r=0;r<4;r++)
          sP[w][g*16 + quad*4 + r][jt*16 + col] = bf16_bits(sv[g][jt][r]);
    asm volatile("s_waitcnt lgkmcnt(0)" ::: "memory");  // same-wave RAW on sP

    short8 aP[2][2];
    #pragma unroll
    for (int g=0;g<2;g++)
      #pragma unroll
      for (int ks2=0;ks2<2;ks2++)
        aP[g][ks2] = *(const short8*)&sP[w][g*16 + col][ks2*32 + quad*8];

    // ---- PV: O[2x16 i x 256 c] += P[16 x 64] * featT[64 x 256]; bF read feeds 2 MFMAs
    #pragma unroll
    for (int ks2=0; ks2<2; ks2++) {
      #pragma unroll
      for (int ct=0;ct<16;ct++) {
        int c = ct*16 + col;
        int slot = (ks2*4 + quad) ^ (c & 7);
        short8 bF = *(const short8*)&sF[buf][c*64 + slot*8];
        o[0][ct] = __builtin_amdgcn_mfma_f32_16x16x32_bf16(aP[0][ks2], bF, o[0][ct], 0, 0, 0);
        o[1][ct] = __builtin_amdgcn_mfma_f32_16x16x32_bf16(aP[1][ks2], bF, o[1][ct], 0, 0, 0);
      }
    }
  }

  // ---- epilogue: divide by l, multiply by mask[i], store fp32
  #pragma unroll
  for (int g=0;g<2;g++) {
    float minv[4];
    #pragma unroll
    for (int r=0;r<4;r++) minv[r] = m_n[i0 + w*32 + g*16 + quad*4 + r] / lrun[g][r];
    #pragma unroll
    for (int ct=0;ct<16;ct++) {
      f32x4 v;
      v[0]=o[g][ct][0]*minv[0]; v[1]=o[g][ct][1]*minv[1];
      v[2]=o[g][ct][2]*minv[2]; v[3]=o[g][ct][3]*minv[3];
      *(f32x4*)(out + ((size_t)n*CF + ct*16 + col)*HWX + i0 + w*32 + g*16 + quad*4) = v;
    }
  }
}

extern "C" void kernel_launch(void* const* d_in, const int* in_sizes, int n_in,
                              void* d_out, int out_size, void* d_ws, size_t ws_size,
                              hipStream_t stream) {
  const float* x    = (const float*)d_in[0];
  const float* mask = (const float*)d_in[1];
  const float* rw   = (const float*)d_in[2];
  const float* rg   = (const float*)d_in[3];
  const float* rb   = (const float*)d_in[4];
  const float* rm   = (const float*)d_in[5];
  const float* rv   = (const float*)d_in[6];
  const float* aw   = (const float*)d_in[7];
  const float* ag   = (const float*)d_in[8];
  const float* ab   = (const float*)d_in[9];
  const float* am   = (const float*)d_in[10];
  const float* av   = (const float*)d_in[11];
  float* out = (float*)d_out;
  char* ws = (char*)d_ws;
  float* wf   = (float*)(ws + OFF_W);
  float* bias = (float*)(ws + OFF_BIAS);
  unsigned short* feat = (unsigned short*)(ws + OFF_FEAT);
  unsigned short* qhi  = (unsigned short*)(ws + OFF_QHI);
  unsigned short* qlo  = (unsigned short*)(ws + OFF_QLO);

  hipLaunchKernelGGL(fold_bn_k, dim3(CT), dim3(CIN), 0, stream,
                     rw, rg, rb, rm, rv, aw, ag, ab, am, av, wf, bias);
  hipLaunchKernelGGL(conv_k, dim3(768), dim3(256), 0, stream,
                     x, wf, bias, feat, qhi, qlo);
  hipLaunchKernelGGL(flash_k, dim3(256), dim3(256), 0, stream,
                     qhi, qlo, feat, mask, out);
}

// Round 3
// 378.506 us; speedup vs baseline: 1.2699x; 1.2699x over previous
//
#include <hip/hip_runtime.h>
#include <cstdint>
#include <cstddef>

#define NB 8
#define CIN 256
#define HWX 4096
#define CF 256
#define CA 128
#define CT 384

typedef __attribute__((ext_vector_type(8))) _Float16 half8;
typedef __attribute__((ext_vector_type(8))) short short8;
typedef __attribute__((ext_vector_type(4))) float f32x4;
typedef __attribute__((ext_vector_type(4))) unsigned int u32x4;

// workspace layout (bytes)
#define OFF_W    0                              // 384*256 fp32 folded weights
#define OFF_BIAS (CT*CIN*4)                     // 384 fp32 folded bias
#define OFF_FEAT (OFF_BIAS + 2048)              // [n][256][4096] fp16
#define OFF_Q    (OFF_FEAT + NB*CF*HWX*2)       // [n][4096][128] fp16

__device__ inline unsigned short f16_bits(float f) {
  _Float16 h = (_Float16)f;
  return __builtin_bit_cast(unsigned short, h);
}
__device__ inline half8 ld_half8(const unsigned short* p) {
  short8 r = *(const short8*)p;
  return __builtin_bit_cast(half8, r);
}

// async global->LDS, 16B per lane. LDS side is wave-uniform base + lane*16,
// so swizzle must go on the GLOBAL address side (m104/m108).
__device__ inline void g2l16(const void* g, void* l) {
  __builtin_amdgcn_global_load_lds(
      (const __attribute__((address_space(1))) unsigned int*)g,
      (__attribute__((address_space(3))) unsigned int*)l, 16, 0, 0);
}

// ---------------- kernel 1: fold BN into weights ----------------
__global__ __launch_bounds__(256) void fold_bn_k(
    const float* __restrict__ rw, const float* __restrict__ rg,
    const float* __restrict__ rb, const float* __restrict__ rm, const float* __restrict__ rv,
    const float* __restrict__ aw, const float* __restrict__ ag,
    const float* __restrict__ ab2, const float* __restrict__ am, const float* __restrict__ av,
    float* __restrict__ wf, float* __restrict__ bias) {
  int o = blockIdx.x, k = threadIdx.x;
  const float* wsrc; float g, b, m, v;
  if (o < CF) { wsrc = rw + (size_t)o*CIN; g = rg[o]; b = rb[o]; m = rm[o]; v = rv[o]; }
  else { int oa = o - CF; wsrc = aw + (size_t)oa*CIN; g = ag[oa]; b = ab2[oa]; m = am[oa]; v = av[oa]; }
  float inv = g / sqrtf(v + 1e-5f);
  wf[(size_t)o*CIN + k] = wsrc[k] * inv;
  if (k == 0) bias[o] = b - m*inv;
}

// ---------------- kernel 2: fp32 conv(1x1)+BN+ReLU GEMM ----------------
// grid 768 = 8n * 3 och-tiles(128) * 32 pos-tiles(128); 256 thr, 8x8 per thread
__global__ __launch_bounds__(256) void conv_k(
    const float* __restrict__ x, const float* __restrict__ wf,
    const float* __restrict__ bias, unsigned short* __restrict__ feat,
    unsigned short* __restrict__ q) {
  __shared__ float w_s[16][132];   // [k][oc], padded
  __shared__ float x_s[16][132];   // [k][pos], padded
  int b = blockIdx.x;
  int n = b / 96, rem = b % 96;
  int ot = rem / 32, pt = rem % 32;
  int oc0 = ot*128, p0 = pt*128;
  int t = threadIdx.x, ty = t >> 4, tx = t & 15;
  const float* xn = x + (size_t)n*CIN*HWX;
  float acc[8][8];
  #pragma unroll
  for (int i=0;i<8;i++)
    #pragma unroll
    for (int j=0;j<8;j++) acc[i][j]=0.f;

  for (int k0=0; k0<CIN; k0+=16) {
    __syncthreads();
    #pragma unroll
    for (int pass=0; pass<2; pass++) {
      int idx = pass*256+t, oc = idx>>2, kq = idx&3;
      f32x4 wv = *(const f32x4*)(wf + (size_t)(oc0+oc)*CIN + k0 + kq*4);
      w_s[kq*4+0][oc]=wv.x; w_s[kq*4+1][oc]=wv.y; w_s[kq*4+2][oc]=wv.z; w_s[kq*4+3][oc]=wv.w;
    }
    #pragma unroll
    for (int pass=0; pass<2; pass++) {
      int idx = pass*256+t, row = idx>>5, cc = idx&31;
      f32x4 xv = *(const f32x4*)(xn + (size_t)(k0+row)*HWX + p0 + cc*4);
      *(f32x4*)&x_s[row][cc*4] = xv;
    }
    __syncthreads();
    #pragma unroll
    for (int kk=0; kk<16; kk++) {
      float a[8], bb[8];
      *(f32x4*)&a[0]  = *(const f32x4*)&w_s[kk][ty*8];
      *(f32x4*)&a[4]  = *(const f32x4*)&w_s[kk][ty*8+4];
      *(f32x4*)&bb[0] = *(const f32x4*)&x_s[kk][tx*8];
      *(f32x4*)&bb[4] = *(const f32x4*)&x_s[kk][tx*8+4];
      #pragma unroll
      for (int i=0;i<8;i++)
        #pragma unroll
        for (int j=0;j<8;j++) acc[i][j] = fmaf(a[i], bb[j], acc[i][j]);
    }
  }

  int posb = p0 + tx*8;
  float bs[8];
  #pragma unroll
  for (int i=0;i<8;i++) bs[i] = bias[oc0 + ty*8 + i];

  if (oc0 < CF) {
    // feat path: [n][c][pos] fp16
    #pragma unroll
    for (int i=0;i<8;i++) {
      int oc = oc0 + ty*8 + i;
      alignas(16) unsigned short u[8];
      #pragma unroll
      for (int j=0;j<8;j++) {
        float vv = fmaxf(acc[i][j] + bs[i], 0.f);
        u[j] = f16_bits(vv);
      }
      *(u32x4*)(feat + (size_t)n*CF*HWX + (size_t)oc*HWX + posb) = *(const u32x4*)u;
    }
  } else {
    // q path: [n][pos][c] fp16
    int cb = oc0 - CF + ty*8;
    #pragma unroll
    for (int j=0;j<8;j++) {
      alignas(16) unsigned short uh[8];
      #pragma unroll
      for (int i=0;i<8;i++) {
        float vv = fmaxf(acc[i][j] + bs[i], 0.f);
        uh[i] = f16_bits(vv);
      }
      *(u32x4*)(q + ((size_t)n*HWX + posb + j)*CA + cb) = *(const u32x4*)uh;
    }
  }
}

// ---------------- kernel 3: flash attention ----------------
// grid 512 = 8n x 64 i-tiles (BM=64); 2 blocks/CU.
// Phase 1 (per iter): wave w computes S rows [w*16,w*16+16) x 64 j, softmax, P->sP (block-shared).
// Phase 2: wave w computes O[all 64 i][c-quarter w] from sP + sF  (2 MFMAs per b128 read).
// 192 MFMA/block-iter = algorithmic minimum, zero duplication.
__global__ __launch_bounds__(256, 2) void flash_k(
    const unsigned short* __restrict__ q, const unsigned short* __restrict__ feat,
    const float* __restrict__ mask, float* __restrict__ out) {
  __shared__ alignas(16) unsigned short sQ[64*128];   // j-tile q fp16, octet-swizzled rows
  __shared__ alignas(16) unsigned short sF[256*64];   // feat tile [c][j] fp16, octet-swizzled
  __shared__ alignas(16) unsigned short sP[64][72];   // block-shared P (A-layout), pad 72
  __shared__ float sAlpha[64];
  __shared__ float sM[64];
  int b = blockIdx.x;
  int n = b & 7, it = b >> 3;         // n == XCD for L2 locality
  int i0 = it * 64;
  int t = threadIdx.x;
  int w = t >> 6, lane = t & 63, quad = lane >> 4, col = lane & 15;
  const unsigned short* q_n = q + (size_t)n*HWX*CA;
  const unsigned short* f_n = feat + (size_t)n*CF*HWX;
  const float* m_n = mask + (size_t)n*HWX;
  const int rloc = t >> 4, oct16 = t & 15;
  const int frow = t >> 3, oct8 = t & 7;

  // staging: sQ+mask consumed in phase 1 (issued after barrier B of prev iter),
  //          sF consumed in phase 2 (issued after barrier A of this iter).
  auto stage_Q = [&](int j0) {
    #pragma unroll
    for (int c=0;c<4;c++) {
      int row = c*16 + rloc;
      int og = oct16 ^ (row & 15);
      g2l16(q_n + (size_t)(j0+row)*CA + og*8, &sQ[(size_t)row*128 + oct16*8]);
    }
    if (t < 16) g2l16(m_n + j0 + t*4, &sM[t*4]);
  };
  auto stage_F = [&](int j0) {
    #pragma unroll
    for (int p=0;p<8;p++) {
      int row = p*32 + frow;
      int og = oct8 ^ (row & 7);
      g2l16(f_n + (size_t)row*HWX + j0 + og*8, &sF[(size_t)row*64 + oct8*8]);
    }
  };

  // A fragments for QK (this wave's 16 i rows), constant over the j loop
  half8 ah[4];
  {
    int arow = i0 + w*16 + col;
    #pragma unroll
    for (int ks=0; ks<4; ks++)
      ah[ks] = ld_half8(q_n + (size_t)arow*CA + ks*32 + quad*8);
  }
  f32x4 fzero = {0.f,0.f,0.f,0.f};
  f32x4 o[4][4];                      // [i-group][c-tile]
  #pragma unroll
  for (int ig=0;ig<4;ig++)
    #pragma unroll
    for (int ct=0;ct<4;ct++) o[ig][ct] = fzero;
  float mrun[4], lrun[4];
  #pragma unroll
  for (int r=0;r<4;r++){ mrun[r] = -INFINITY; lrun[r] = 0.f; }
  const float inv_s = 1.0f/(1e-8f + sqrtf(128.0f));

  stage_Q(0);
  for (int ji = 0; ji < 64; ji++) {
    int j0 = ji*64;
    __syncthreads();                  // A: sQ(ji)+sM(ji) ready; PV(ji-1) done with sF/sP/sAlpha
    stage_F(j0);                      // overlaps QK+softmax, drained at barrier B

    // ---- QK^T: S[16 i x 64 j], fp16 single
    f32x4 s[4];
    #pragma unroll
    for (int jt=0;jt<4;jt++) s[jt] = fzero;
    #pragma unroll
    for (int jt=0;jt<4;jt++) {
      int row = jt*16 + col;
      #pragma unroll
      for (int ks=0; ks<4; ks++) {
        int slot = (ks*4 + quad) ^ (row & 15);
        half8 bq = ld_half8(&sQ[row*128 + slot*8]);
        s[jt] = __builtin_amdgcn_mfma_f32_16x16x32_f16(ah[ks], bq, s[jt], 0, 0, 0);
      }
    }

    // ---- online softmax; C/D layout: row = quad*4+r (i), col = lane&15 (j)
    float mj[4];
    #pragma unroll
    for (int jt=0;jt<4;jt++) mj[jt] = (sM[jt*16+col] - 1.f) * 1e8f;
    float sv[4][4], alpha[4];
    #pragma unroll
    for (int jt=0;jt<4;jt++)
      #pragma unroll
      for (int r=0;r<4;r++) sv[jt][r] = s[jt][r]*inv_s + mj[jt];
    #pragma unroll
    for (int r=0;r<4;r++) {
      float mx = fmaxf(fmaxf(sv[0][r],sv[1][r]), fmaxf(sv[2][r],sv[3][r]));
      mx = fmaxf(mx, __shfl_xor(mx, 1, 64));
      mx = fmaxf(mx, __shfl_xor(mx, 2, 64));
      mx = fmaxf(mx, __shfl_xor(mx, 4, 64));
      mx = fmaxf(mx, __shfl_xor(mx, 8, 64));
      float mn = fmaxf(mrun[r], mx);
      alpha[r] = __expf(mrun[r] - mn);
      mrun[r] = mn;
      float ss = 0.f;
      #pragma unroll
      for (int jt=0;jt<4;jt++) { float p = __expf(sv[jt][r] - mn); sv[jt][r] = p; ss += p; }
      ss += __shfl_xor(ss, 1, 64);
      ss += __shfl_xor(ss, 2, 64);
      ss += __shfl_xor(ss, 4, 64);
      ss += __shfl_xor(ss, 8, 64);
      lrun[r] = lrun[r]*alpha[r] + ss;
      if (col == 0) sAlpha[w*16 + quad*4 + r] = alpha[r];
      #pragma unroll
      for (int jt=0;jt<4;jt++)
        sP[w*16 + quad*4 + r][jt*16 + col] = f16_bits(sv[jt][r]);
    }

    __syncthreads();                  // B: sF(ji) ready; sP/sAlpha visible; QK done with sQ
    if (ji + 1 < 64) stage_Q(j0+64);  // overlaps PV, drained at next barrier A

    // ---- PV: wave w owns c in [w*64,(w+1)*64) for ALL 64 i rows
    f32x4 av[4];
    bool need = false;
    #pragma unroll
    for (int ig=0;ig<4;ig++) {
      av[ig] = *(const f32x4*)&sAlpha[ig*16 + quad*4];
      need = need | (av[ig][0]!=1.f) | (av[ig][1]!=1.f) | (av[ig][2]!=1.f) | (av[ig][3]!=1.f);
    }
    if (__ballot(need)) {
      #pragma unroll
      for (int ig=0;ig<4;ig++)
        #pragma unroll
        for (int ct=0;ct<4;ct++) {
          o[ig][ct][0]*=av[ig][0]; o[ig][ct][1]*=av[ig][1];
          o[ig][ct][2]*=av[ig][2]; o[ig][ct][3]*=av[ig][3];
        }
    }
    half8 aP[4][2];
    #pragma unroll
    for (int ig=0;ig<4;ig++)
      #pragma unroll
      for (int ks2=0;ks2<2;ks2++)
        aP[ig][ks2] = ld_half8(&sP[ig*16 + col][ks2*32 + quad*8]);
    #pragma unroll
    for (int ks2=0; ks2<2; ks2++) {
      #pragma unroll
      for (int ct=0;ct<4;ct++) {
        int c = w*64 + ct*16 + col;
        int slot = (ks2*4 + quad) ^ (c & 7);
        half8 bF = ld_half8(&sF[c*64 + slot*8]);
        #pragma unroll
        for (int ig=0;ig<4;ig++)
          o[ig][ct] = __builtin_amdgcn_mfma_f32_16x16x32_f16(aP[ig][ks2], bF, o[ig][ct], 0, 0, 0);
      }
    }
  }

  // ---- epilogue: broadcast l via LDS, divide, multiply by mask[i], store fp32
  __syncthreads();
  #pragma unroll
  for (int r=0;r<4;r++)
    if (col == 0) sAlpha[w*16 + quad*4 + r] = lrun[r];
  __syncthreads();
  #pragma unroll
  for (int ig=0;ig<4;ig++) {
    f32x4 lv = *(const f32x4*)&sAlpha[ig*16 + quad*4];
    f32x4 mv = *(const f32x4*)(m_n + i0 + ig*16 + quad*4);
    f32x4 minv;
    #pragma unroll
    for (int r=0;r<4;r++) minv[r] = mv[r] / lv[r];
    #pragma unroll
    for (int ct=0;ct<4;ct++) {
      int c = w*64 + ct*16 + col;
      f32x4 v;
      #pragma unroll
      for (int r=0;r<4;r++) v[r] = o[ig][ct][r] * minv[r];
      *(f32x4*)(out + ((size_t)n*CF + c)*HWX + i0 + ig*16 + quad*4) = v;
    }
  }
}

extern "C" void kernel_launch(void* const* d_in, const int* in_sizes, int n_in,
                              void* d_out, int out_size, void* d_ws, size_t ws_size,
                              hipStream_t stream) {
  const float* x    = (const float*)d_in[0];
  const float* mask = (const float*)d_in[1];
  const float* rw   = (const float*)d_in[2];
  const float* rg   = (const float*)d_in[3];
  const float* rb   = (const float*)d_in[4];
  const float* rm   = (const float*)d_in[5];
  const float* rv   = (const float*)d_in[6];
  const float* aw   = (const float*)d_in[7];
  const float* ag   = (const float*)d_in[8];
  const float* ab   = (const float*)d_in[9];
  const float* am   = (const float*)d_in[10];
  const float* av   = (const float*)d_in[11];
  float* out = (float*)d_out;
  char* ws = (char*)d_ws;
  float* wf   = (float*)(ws + OFF_W);
  float* bias = (float*)(ws + OFF_BIAS);
  unsigned short* feat = (unsigned short*)(ws + OFF_FEAT);
  unsigned short* q    = (unsigned short*)(ws + OFF_Q);

  hipLaunchKernelGGL(fold_bn_k, dim3(CT), dim3(CIN), 0, stream,
                     rw, rg, rb, rm, rv, aw, ag, ab, am, av, wf, bias);
  hipLaunchKernelGGL(conv_k, dim3(768), dim3(256), 0, stream,
                     x, wf, bias, feat, q);
  hipLaunchKernelGGL(flash_k, dim3(512), dim3(256), 0, stream,
                     q, feat, mask, out);
}

// Round 4
// 339.110 us; speedup vs baseline: 1.4174x; 1.1162x over previous
//
#include <hip/hip_runtime.h>
#include <cstdint>
#include <cstddef>

#define NB 8
#define CIN 256
#define HWX 4096
#define CF 256
#define CA 128
#define CT 384

typedef __attribute__((ext_vector_type(8))) _Float16 half8;
typedef __attribute__((ext_vector_type(8))) short short8;
typedef __attribute__((ext_vector_type(4))) float f32x4;
typedef __attribute__((ext_vector_type(4))) unsigned int u32x4;

// workspace layout (bytes)
#define OFF_W    0                              // 384*256 fp32 folded weights
#define OFF_BIAS (CT*CIN*4)                     // 384 fp32 folded bias
#define OFF_FEAT (OFF_BIAS + 2048)              // [n][256][4096] fp16
#define OFF_Q    (OFF_FEAT + NB*CF*HWX*2)       // [n][4096][128] fp16
#define OFF_NORM (OFF_Q + NB*HWX*CA*2)          // [n][4096] fp32 row norms of q
#define OFF_G    (OFF_NORM + NB*HWX*4)          // [n] uint (max norm bits)

__device__ inline unsigned short f16_bits(float f) {
  _Float16 h = (_Float16)f;
  return __builtin_bit_cast(unsigned short, h);
}
__device__ inline half8 ld_half8(const unsigned short* p) {
  short8 r = *(const short8*)p;
  return __builtin_bit_cast(half8, r);
}

// async global->LDS, 16B per lane. LDS side is wave-uniform base + lane*16,
// so swizzle must go on the GLOBAL address side (m104/m108).
__device__ inline void g2l16(const void* g, void* l) {
  __builtin_amdgcn_global_load_lds(
      (const __attribute__((address_space(1))) unsigned int*)g,
      (__attribute__((address_space(3))) unsigned int*)l, 16, 0, 0);
}

// ---------------- kernel 1: fold BN into weights (+ zero G) ----------------
__global__ __launch_bounds__(256) void fold_bn_k(
    const float* __restrict__ rw, const float* __restrict__ rg,
    const float* __restrict__ rb, const float* __restrict__ rm, const float* __restrict__ rv,
    const float* __restrict__ aw, const float* __restrict__ ag,
    const float* __restrict__ ab2, const float* __restrict__ am, const float* __restrict__ av,
    float* __restrict__ wf, float* __restrict__ bias, unsigned* __restrict__ Gmax) {
  int o = blockIdx.x, k = threadIdx.x;
  if (o == 0 && k < NB) Gmax[k] = 0u;
  const float* wsrc; float g, b, m, v;
  if (o < CF) { wsrc = rw + (size_t)o*CIN; g = rg[o]; b = rb[o]; m = rm[o]; v = rv[o]; }
  else { int oa = o - CF; wsrc = aw + (size_t)oa*CIN; g = ag[oa]; b = ab2[oa]; m = am[oa]; v = av[oa]; }
  float inv = g / sqrtf(v + 1e-5f);
  wf[(size_t)o*CIN + k] = wsrc[k] * inv;
  if (k == 0) bias[o] = b - m*inv;
}

// ---------------- kernel 2: fp32 conv(1x1)+BN+ReLU GEMM ----------------
// grid 768 = 8n * 3 och-tiles(128) * 32 pos-tiles(128); 256 thr, 8x8 per thread
// q-tile blocks additionally compute per-position row norms + per-n max norm.
__global__ __launch_bounds__(256) void conv_k(
    const float* __restrict__ x, const float* __restrict__ wf,
    const float* __restrict__ bias, unsigned short* __restrict__ feat,
    unsigned short* __restrict__ q, float* __restrict__ normq,
    unsigned* __restrict__ Gmax) {
  __shared__ float w_s[16][132];   // [k][oc], padded
  __shared__ float x_s[16][132];   // [k][pos], padded
  __shared__ float normS[128];
  int b = blockIdx.x;
  int n = b / 96, rem = b % 96;
  int ot = rem / 32, pt = rem % 32;
  int oc0 = ot*128, p0 = pt*128;
  int t = threadIdx.x, ty = t >> 4, tx = t & 15;
  const float* xn = x + (size_t)n*CIN*HWX;
  float acc[8][8];
  #pragma unroll
  for (int i=0;i<8;i++)
    #pragma unroll
    for (int j=0;j<8;j++) acc[i][j]=0.f;

  for (int k0=0; k0<CIN; k0+=16) {
    __syncthreads();
    #pragma unroll
    for (int pass=0; pass<2; pass++) {
      int idx = pass*256+t, oc = idx>>2, kq = idx&3;
      f32x4 wv = *(const f32x4*)(wf + (size_t)(oc0+oc)*CIN + k0 + kq*4);
      w_s[kq*4+0][oc]=wv.x; w_s[kq*4+1][oc]=wv.y; w_s[kq*4+2][oc]=wv.z; w_s[kq*4+3][oc]=wv.w;
    }
    #pragma unroll
    for (int pass=0; pass<2; pass++) {
      int idx = pass*256+t, row = idx>>5, cc = idx&31;
      f32x4 xv = *(const f32x4*)(xn + (size_t)(k0+row)*HWX + p0 + cc*4);
      *(f32x4*)&x_s[row][cc*4] = xv;
    }
    __syncthreads();
    #pragma unroll
    for (int kk=0; kk<16; kk++) {
      float a[8], bb[8];
      *(f32x4*)&a[0]  = *(const f32x4*)&w_s[kk][ty*8];
      *(f32x4*)&a[4]  = *(const f32x4*)&w_s[kk][ty*8+4];
      *(f32x4*)&bb[0] = *(const f32x4*)&x_s[kk][tx*8];
      *(f32x4*)&bb[4] = *(const f32x4*)&x_s[kk][tx*8+4];
      #pragma unroll
      for (int i=0;i<8;i++)
        #pragma unroll
        for (int j=0;j<8;j++) acc[i][j] = fmaf(a[i], bb[j], acc[i][j]);
    }
  }

  int posb = p0 + tx*8;
  float bs[8];
  #pragma unroll
  for (int i=0;i<8;i++) bs[i] = bias[oc0 + ty*8 + i];

  if (oc0 < CF) {
    // feat path: [n][c][pos] fp16
    #pragma unroll
    for (int i=0;i<8;i++) {
      int oc = oc0 + ty*8 + i;
      alignas(16) unsigned short u[8];
      #pragma unroll
      for (int j=0;j<8;j++) {
        float vv = fmaxf(acc[i][j] + bs[i], 0.f);
        u[j] = f16_bits(vv);
      }
      *(u32x4*)(feat + (size_t)n*CF*HWX + (size_t)oc*HWX + posb) = *(const u32x4*)u;
    }
  } else {
    // q path: [n][pos][c] fp16 + row-norm computation
    __syncthreads();
    if (t < 128) normS[t] = 0.f;
    __syncthreads();
    int cb = oc0 - CF + ty*8;
    float ns[8];
    #pragma unroll
    for (int j=0;j<8;j++) {
      alignas(16) unsigned short uh[8];
      float s2 = 0.f;
      #pragma unroll
      for (int i=0;i<8;i++) {
        float vv = fmaxf(acc[i][j] + bs[i], 0.f);
        uh[i] = f16_bits(vv);
        s2 += vv*vv;
      }
      ns[j] = s2;
      *(u32x4*)(q + ((size_t)n*HWX + posb + j)*CA + cb) = *(const u32x4*)uh;
    }
    #pragma unroll
    for (int j=0;j<8;j++) atomicAdd(&normS[tx*8+j], ns[j]);
    __syncthreads();
    if (t < 128) {
      float nv = sqrtf(normS[t]);
      normq[(size_t)n*HWX + p0 + t] = nv;
      atomicMax(Gmax + n, __float_as_uint(nv));   // norms >= 0: uint order == float order
    }
  }
}

// ---------------- kernel 3: flash attention, max-free softmax ----------------
// grid 512 = 8n x 64 i-tiles (BM=64).
// Per-row static bound C_i = |q_i|*G/sqrt(128) >= max_j E_ij (Cauchy-Schwarz), so
// P = exp(E - C_i + 5) needs no running max (P <= e^5, fp16-safe); o/l cancels the shift.
// Phase 1: wave w computes S rows [w*16..+16) x 64 j, exp, P->sP (block-shared).
// Phase 2: wave w computes O[all 64 i][c-quarter w]; F B-frags loaded DIRECT from L2
// (perfectly sector-coalesced, zero duplication) -- no sF staging, LDS 25.7 KB.
__global__ __launch_bounds__(256, 3) void flash_k(
    const unsigned short* __restrict__ q, const unsigned short* __restrict__ feat,
    const float* __restrict__ mask, const float* __restrict__ normq,
    const unsigned* __restrict__ Gmax, float* __restrict__ out) {
  __shared__ alignas(16) unsigned short sQ[64*128];   // j-tile q fp16, octet-swizzled rows
  __shared__ alignas(16) unsigned short sP[64][72];   // block-shared P (A-layout), pad 72
  __shared__ float sM[64];                            // mask j-tile; reused for l at end
  int b = blockIdx.x;
  int n = b & 7, it = b >> 3;         // n == XCD for L2 locality
  int i0 = it * 64;
  int t = threadIdx.x;
  int w = t >> 6, lane = t & 63, quad = lane >> 4, col = lane & 15;
  const unsigned short* q_n = q + (size_t)n*HWX*CA;
  const unsigned short* f_n = feat + (size_t)n*CF*HWX;
  const float* m_n = mask + (size_t)n*HWX;
  const int rloc = t >> 4, oct16 = t & 15;
  const float inv_s = 1.0f/(1e-8f + sqrtf(128.0f));

  auto stage_Q = [&](int j0) {
    #pragma unroll
    for (int c=0;c<4;c++) {
      int row = c*16 + rloc;
      int og = oct16 ^ (row & 15);
      g2l16(q_n + (size_t)(j0+row)*CA + og*8, &sQ[(size_t)row*128 + oct16*8]);
    }
    if (t < 16) g2l16(m_n + j0 + t*4, &sM[t*4]);
  };

  // A fragments for QK (this wave's 16 i rows), constant over the j loop
  half8 ah[4];
  {
    int arow = i0 + w*16 + col;
    #pragma unroll
    for (int ks=0; ks<4; ks++)
      ah[ks] = ld_half8(q_n + (size_t)arow*CA + ks*32 + quad*8);
  }
  // per-row exp shift: C_i - 5
  float Gn = __uint_as_float(Gmax[n]);
  float cvals[4];
  #pragma unroll
  for (int r=0;r<4;r++)
    cvals[r] = normq[(size_t)n*HWX + i0 + w*16 + quad*4 + r] * Gn * inv_s - 5.0f;

  f32x4 fzero = {0.f,0.f,0.f,0.f};
  f32x4 o[4][4];                      // [i-group][c-tile]
  #pragma unroll
  for (int ig=0;ig<4;ig++)
    #pragma unroll
    for (int ct=0;ct<4;ct++) o[ig][ct] = fzero;
  float lrun[4] = {0.f,0.f,0.f,0.f};

  stage_Q(0);
  for (int ji = 0; ji < 64; ji++) {
    int j0 = ji*64;
    __syncthreads();                  // A: sQ(ji)+sM(ji) ready; PV(ji-1) done with sP

    // ---- QK^T: S[16 i x 64 j], fp16
    f32x4 s[4];
    #pragma unroll
    for (int jt=0;jt<4;jt++) s[jt] = fzero;
    #pragma unroll
    for (int jt=0;jt<4;jt++) {
      int row = jt*16 + col;
      #pragma unroll
      for (int ks=0; ks<4; ks++) {
        int slot = (ks*4 + quad) ^ (row & 15);
        half8 bq = ld_half8(&sQ[row*128 + slot*8]);
        s[jt] = __builtin_amdgcn_mfma_f32_16x16x32_f16(ah[ks], bq, s[jt], 0, 0, 0);
      }
    }

    // ---- max-free softmax: P = exp(E*inv_s + maskterm - C_i + 5); l += P
    #pragma unroll
    for (int jt=0;jt<4;jt++) {
      float mj = (sM[jt*16+col] - 1.f) * 1e8f;
      #pragma unroll
      for (int r=0;r<4;r++) {
        float p = __expf(s[jt][r]*inv_s + mj - cvals[r]);
        lrun[r] += p;
        sP[w*16 + quad*4 + r][jt*16 + col] = f16_bits(p);
      }
    }

    __syncthreads();                  // B: sP visible; all QK reads of sQ done
    if (ji + 1 < 64) stage_Q(j0+64);  // overlaps PV, drained at next barrier A

    // ---- PV: wave w owns c in [w*64,(w+1)*64) for ALL 64 i rows.
    // B-frags direct from global (L2): lane reads 16B at feat[c][j0+k..k+8],
    // 16 c-rows x 64B contiguous per instr -> full-sector coalescing.
    #pragma unroll
    for (int ks2=0; ks2<2; ks2++) {
      half8 aP[4];
      #pragma unroll
      for (int ig=0;ig<4;ig++)
        aP[ig] = ld_half8(&sP[ig*16 + col][ks2*32 + quad*8]);
      half8 bF[4];
      #pragma unroll
      for (int ct=0;ct<4;ct++) {
        int c = w*64 + ct*16 + col;
        bF[ct] = ld_half8(f_n + (size_t)c*HWX + j0 + ks2*32 + quad*8);
      }
      #pragma unroll
      for (int ct=0;ct<4;ct++)
        #pragma unroll
        for (int ig=0;ig<4;ig++)
          o[ig][ct] = __builtin_amdgcn_mfma_f32_16x16x32_f16(aP[ig], bF[ct], o[ig][ct], 0, 0, 0);
    }
  }

  // ---- final l: reduce over the 16 j-cols, broadcast via sM, divide, mask, store
  #pragma unroll
  for (int r=0;r<4;r++) {
    float ss = lrun[r];
    ss += __shfl_xor(ss, 1, 64);
    ss += __shfl_xor(ss, 2, 64);
    ss += __shfl_xor(ss, 4, 64);
    ss += __shfl_xor(ss, 8, 64);
    lrun[r] = ss;
  }
  __syncthreads();
  #pragma unroll
  for (int r=0;r<4;r++)
    if (col == 0) sM[w*16 + quad*4 + r] = lrun[r];
  __syncthreads();
  #pragma unroll
  for (int ig=0;ig<4;ig++) {
    f32x4 lv = *(const f32x4*)&sM[ig*16 + quad*4];
    f32x4 mv = *(const f32x4*)(m_n + i0 + ig*16 + quad*4);
    f32x4 minv;
    #pragma unroll
    for (int r=0;r<4;r++) minv[r] = mv[r] / lv[r];
    #pragma unroll
    for (int ct=0;ct<4;ct++) {
      int c = w*64 + ct*16 + col;
      f32x4 v;
      #pragma unroll
      for (int r=0;r<4;r++) v[r] = o[ig][ct][r] * minv[r];
      *(f32x4*)(out + ((size_t)n*CF + c)*HWX + i0 + ig*16 + quad*4) = v;
    }
  }
}

extern "C" void kernel_launch(void* const* d_in, const int* in_sizes, int n_in,
                              void* d_out, int out_size, void* d_ws, size_t ws_size,
                              hipStream_t stream) {
  const float* x    = (const float*)d_in[0];
  const float* mask = (const float*)d_in[1];
  const float* rw   = (const float*)d_in[2];
  const float* rg   = (const float*)d_in[3];
  const float* rb   = (const float*)d_in[4];
  const float* rm   = (const float*)d_in[5];
  const float* rv   = (const float*)d_in[6];
  const float* aw   = (const float*)d_in[7];
  const float* ag   = (const float*)d_in[8];
  const float* ab   = (const float*)d_in[9];
  const float* am   = (const float*)d_in[10];
  const float* av   = (const float*)d_in[11];
  float* out = (float*)d_out;
  char* ws = (char*)d_ws;
  float* wf   = (float*)(ws + OFF_W);
  float* bias = (float*)(ws + OFF_BIAS);
  unsigned short* feat = (unsigned short*)(ws + OFF_FEAT);
  unsigned short* q    = (unsigned short*)(ws + OFF_Q);
  float* normq = (float*)(ws + OFF_NORM);
  unsigned* Gmax = (unsigned*)(ws + OFF_G);

  hipLaunchKernelGGL(fold_bn_k, dim3(CT), dim3(CIN), 0, stream,
                     rw, rg, rb, rm, rv, aw, ag, ab, am, av, wf, bias, Gmax);
  hipLaunchKernelGGL(conv_k, dim3(768), dim3(256), 0, stream,
                     x, wf, bias, feat, q, normq, Gmax);
  hipLaunchKernelGGL(flash_k, dim3(512), dim3(256), 0, stream,
                     q, feat, mask, normq, Gmax, out);
}

// Round 5
// 295.154 us; speedup vs baseline: 1.6285x; 1.1489x over previous
//
#include <hip/hip_runtime.h>
#include <cstdint>
#include <cstddef>

#define NB 8
#define CIN 256
#define HWX 4096
#define CF 256
#define CA 128
#define CT 384

typedef __attribute__((ext_vector_type(8))) _Float16 half8;
typedef __attribute__((ext_vector_type(8))) short short8;
typedef __attribute__((ext_vector_type(4))) float f32x4;
typedef __attribute__((ext_vector_type(4))) unsigned int u32x4;

// workspace layout (bytes)
#define OFF_WH   0                              // 384*256 fp16 folded weights
#define OFF_BIAS (CT*CIN*2)                     // 384 fp32 folded bias
#define OFF_FEAT (OFF_BIAS + CT*4)              // [n][256][4096] fp16
#define OFF_Q    (OFF_FEAT + NB*CF*HWX*2)       // [n][4096][128] fp16
#define OFF_NORM (OFF_Q + NB*HWX*CA*2)          // [n][4096] fp32 row norms of q
#define OFF_G    (OFF_NORM + NB*HWX*4)          // [n] uint (max norm bits)

__device__ inline unsigned short f16_bits(float f) {
  _Float16 h = (_Float16)f;
  return __builtin_bit_cast(unsigned short, h);
}
__device__ inline half8 ld_half8(const unsigned short* p) {
  short8 r = *(const short8*)p;
  return __builtin_bit_cast(half8, r);
}

// async global->LDS, 16B per lane; LDS side must be lane-linear (m104/m108),
// swizzle goes on the GLOBAL address.
__device__ inline void g2l16(const void* g, void* l) {
  __builtin_amdgcn_global_load_lds(
      (const __attribute__((address_space(1))) unsigned int*)g,
      (__attribute__((address_space(3))) unsigned int*)l, 16, 0, 0);
}

// ---------------- kernel 1: fold BN into fp16 weights (+ zero G) ----------------
__global__ __launch_bounds__(256) void fold_bn_k(
    const float* __restrict__ rw, const float* __restrict__ rg,
    const float* __restrict__ rb, const float* __restrict__ rm, const float* __restrict__ rv,
    const float* __restrict__ aw, const float* __restrict__ ag,
    const float* __restrict__ ab2, const float* __restrict__ am, const float* __restrict__ av,
    unsigned short* __restrict__ wh, float* __restrict__ bias, unsigned* __restrict__ Gmax) {
  int o = blockIdx.x, k = threadIdx.x;
  if (o == 0 && k < NB) Gmax[k] = 0u;
  const float* wsrc; float g, b, m, v;
  if (o < CF) { wsrc = rw + (size_t)o*CIN; g = rg[o]; b = rb[o]; m = rm[o]; v = rv[o]; }
  else { int oa = o - CF; wsrc = aw + (size_t)oa*CIN; g = ag[oa]; b = ab2[oa]; m = am[oa]; v = av[oa]; }
  float inv = g / sqrtf(v + 1e-5f);
  wh[(size_t)o*CIN + k] = f16_bits(wsrc[k] * inv);
  if (k == 0) bias[o] = b - m*inv;
}

// ---------------- kernel 2: fp16 MFMA conv(1x1)+BN+ReLU ----------------
// grid 512 = 8n x 64 pos-tiles(64). Block tile: [64 pos] x [384 oc] x K=256.
// x staged once (transposed fp32->fp16 into LDS); w B-frags direct from L2.
// Wave w owns oc slab [w*96, w*96+96): acc 4 pos-tiles x 6 oc-tiles.
__global__ __launch_bounds__(256, 2) void conv_k(
    const float* __restrict__ x, const unsigned short* __restrict__ wh,
    const float* __restrict__ bias, unsigned short* __restrict__ feat,
    unsigned short* __restrict__ q, float* __restrict__ normq,
    unsigned* __restrict__ Gmax) {
  __shared__ unsigned short sBuf[18432];  // xT [64 pos][264] | featD [256 oc][72]
  __shared__ unsigned short sQr[64*136];  // qD [64 pos][136]
  int b = blockIdx.x;
  int n = b & 7, pt0 = b >> 3;
  int p0 = pt0 * 64;
  int t = threadIdx.x;
  int w = t >> 6, lane = t & 63, quad = lane >> 4, col = lane & 15;
  const float* xn = x + (size_t)n*CIN*HWX;

  // stage x tile [256 k][64 pos] -> LDS transposed fp16 [pos][k], k-pairs packed
  #pragma unroll
  for (int pass=0; pass<8; pass++) {
    int idx = pass*256 + t;
    int kp = idx >> 4, pq = idx & 15;
    f32x4 a = *(const f32x4*)(xn + (size_t)(2*kp)*HWX + p0 + pq*4);
    f32x4 c = *(const f32x4*)(xn + (size_t)(2*kp+1)*HWX + p0 + pq*4);
    #pragma unroll
    for (int j=0;j<4;j++) {
      int pos = pq*4 + j;
      unsigned dd = (unsigned)f16_bits(a[j]) | ((unsigned)f16_bits(c[j]) << 16);
      *(unsigned*)&sBuf[pos*264 + kp*2] = dd;
    }
  }
  __syncthreads();

  f32x4 fzero = {0.f,0.f,0.f,0.f};
  f32x4 acc[4][6];
  #pragma unroll
  for (int pt=0;pt<4;pt++)
    #pragma unroll
    for (int ot=0;ot<6;ot++) acc[pt][ot] = fzero;

  #pragma unroll
  for (int ks=0; ks<8; ks++) {
    half8 B6[6];
    #pragma unroll
    for (int ot=0;ot<6;ot++)
      B6[ot] = ld_half8(wh + (size_t)(w*96 + ot*16 + col)*CIN + ks*32 + quad*8);
    half8 A4[4];
    #pragma unroll
    for (int pt=0;pt<4;pt++)
      A4[pt] = ld_half8(&sBuf[(pt*16+col)*264 + ks*32 + quad*8]);
    #pragma unroll
    for (int pt=0;pt<4;pt++)
      #pragma unroll
      for (int ot=0;ot<6;ot++)
        acc[pt][ot] = __builtin_amdgcn_mfma_f32_16x16x32_f16(A4[pt], B6[ot], acc[pt][ot], 0, 0, 0);
  }
  __syncthreads();   // all xT reads done; sBuf reused for feat scatter

  // scatter D -> LDS (bias+ReLU fused).  D: pos = pt*16+quad*4+r, oc = w*96+ot*16+col
  float bv[6];
  #pragma unroll
  for (int ot=0;ot<6;ot++) bv[ot] = bias[w*96 + ot*16 + col];
  #pragma unroll
  for (int pt=0;pt<4;pt++)
    #pragma unroll
    for (int ot=0;ot<6;ot++) {
      int oc = w*96 + ot*16 + col;
      #pragma unroll
      for (int r=0;r<4;r++) {
        float v = fmaxf(acc[pt][ot][r] + bv[ot], 0.f);
        int pos = pt*16 + quad*4 + r;
        if (oc < CF) sBuf[oc*72 + pos] = f16_bits(v);
        else         sQr[pos*136 + (oc - CF)] = f16_bits(v);
      }
    }
  __syncthreads();

  // feat readback: thread t = oc, contiguous 128B row store
  {
    const unsigned short* src = &sBuf[t*72];
    unsigned short* dst = feat + (size_t)n*CF*HWX + (size_t)t*HWX + p0;
    #pragma unroll
    for (int s=0;s<8;s++)
      *(u32x4*)(dst + s*8) = *(const u32x4*)(src + s*8);
  }
  // q readback + row norms
  {
    int pos = t >> 2, seg = t & 3;
    const unsigned short* src = &sQr[pos*136 + seg*32];
    unsigned short* dst = q + ((size_t)n*HWX + p0 + pos)*CA + seg*32;
    float s2 = 0.f;
    #pragma unroll
    for (int u=0;u<4;u++) {
      short8 v = *(const short8*)(src + u*8);
      *(short8*)(dst + u*8) = v;
      half8 h = __builtin_bit_cast(half8, v);
      #pragma unroll
      for (int e=0;e<8;e++) { float fe = (float)h[e]; s2 += fe*fe; }
    }
    s2 += __shfl_xor(s2, 1, 64);
    s2 += __shfl_xor(s2, 2, 64);
    if (seg == 0) {
      float nv = sqrtf(s2);
      normq[(size_t)n*HWX + p0 + pos] = nv;
      atomicMax(Gmax + n, __float_as_uint(nv));   // norms >= 0: uint order == float order
    }
  }
}

// ---------------- kernel 3: flash attention, 512 threads ----------------
// grid 512 = 8n x 64 i-tiles (BM=64); 8 waves/block -> 16 waves/CU (4/SIMD).
// Wave (wq = w&3, wh = w>>2): QK computes S[wq rows][wh j-half]; PV owns c-slab w*32.
// Max-free softmax via per-row Cauchy-Schwarz bound (R4). feat B-frags prefetched
// into VGPRs right after barrier A so L2 latency hides under QK+softmax.
__global__ __launch_bounds__(512, 4) void flash_k(
    const unsigned short* __restrict__ q, const unsigned short* __restrict__ feat,
    const float* __restrict__ mask, const float* __restrict__ normq,
    const unsigned* __restrict__ Gmax, float* __restrict__ out) {
  __shared__ alignas(16) unsigned short sQ[64*128];   // j-tile q fp16, octet-swizzled
  __shared__ alignas(16) unsigned short sP[64][72];   // block-shared P (A-layout)
  __shared__ float sM[64];                            // mask j-tile
  __shared__ float sL[2][64];                         // per-half l sums (epilogue)
  int b = blockIdx.x;
  int n = b & 7, it = b >> 3;         // n == XCD for L2 locality
  int i0 = it * 64;
  int t = threadIdx.x;
  int w = t >> 6, lane = t & 63, quad = lane >> 4, col = lane & 15;
  int wq = w & 3, wh = w >> 2;
  const unsigned short* q_n = q + (size_t)n*HWX*CA;
  const unsigned short* f_n = feat + (size_t)n*CF*HWX;
  const float* m_n = mask + (size_t)n*HWX;
  const int rloc = (t >> 4) & 31, oct16 = t & 15;
  const float inv_s = 1.0f/(1e-8f + sqrtf(128.0f));

  auto stage_Q = [&](int j0) {
    #pragma unroll
    for (int c=0;c<2;c++) {
      int row = c*32 + rloc;
      int og = oct16 ^ (row & 15);
      g2l16(q_n + (size_t)(j0+row)*CA + og*8, &sQ[(size_t)row*128 + oct16*8]);
    }
    if (t < 16) g2l16(m_n + j0 + t*4, &sM[t*4]);
  };

  // A fragments for QK (this wave's 16 i rows)
  half8 ah[4];
  {
    int arow = i0 + wq*16 + col;
    #pragma unroll
    for (int ks=0; ks<4; ks++)
      ah[ks] = ld_half8(q_n + (size_t)arow*CA + ks*32 + quad*8);
  }
  // per-row exp shift: C_i - 5
  float Gn = __uint_as_float(Gmax[n]);
  float cvals[4];
  #pragma unroll
  for (int r=0;r<4;r++)
    cvals[r] = normq[(size_t)n*HWX + i0 + wq*16 + quad*4 + r] * Gn * inv_s - 5.0f;

  f32x4 fzero = {0.f,0.f,0.f,0.f};
  f32x4 o[4][2];                      // [i-group][c-tile], c-slab = w*32
  #pragma unroll
  for (int ig=0;ig<4;ig++) { o[ig][0] = fzero; o[ig][1] = fzero; }
  float lrun[4] = {0.f,0.f,0.f,0.f};

  stage_Q(0);
  for (int ji = 0; ji < 64; ji++) {
    int j0 = ji*64;
    __syncthreads();                  // A: sQ(ji)+sM(ji) ready; PV(ji-1) done with sP

    // prefetch PV B-frags (global/L2) -- consumed after barrier B
    half8 bF[2][2];
    #pragma unroll
    for (int ks2=0;ks2<2;ks2++)
      #pragma unroll
      for (int ct=0;ct<2;ct++) {
        int c = w*32 + ct*16 + col;
        bF[ks2][ct] = ld_half8(f_n + (size_t)c*HWX + j0 + ks2*32 + quad*8);
      }

    // ---- QK^T: S[16 i x 32 j] (this wave's half)
    f32x4 s[2];
    s[0] = fzero; s[1] = fzero;
    #pragma unroll
    for (int jt=0;jt<2;jt++) {
      int rowj = wh*32 + jt*16 + col;
      #pragma unroll
      for (int ks=0; ks<4; ks++) {
        int slot = (ks*4 + quad) ^ (rowj & 15);
        half8 bq = ld_half8(&sQ[rowj*128 + slot*8]);
        s[jt] = __builtin_amdgcn_mfma_f32_16x16x32_f16(ah[ks], bq, s[jt], 0, 0, 0);
      }
    }

    // ---- max-free softmax: P = exp(E*inv_s + maskterm - C_i + 5); l += P
    #pragma unroll
    for (int jt=0;jt<2;jt++) {
      float mj = (sM[wh*32 + jt*16 + col] - 1.f) * 1e8f;
      #pragma unroll
      for (int r=0;r<4;r++) {
        float p = __expf(s[jt][r]*inv_s + mj - cvals[r]);
        lrun[r] += p;
        sP[wq*16 + quad*4 + r][wh*32 + jt*16 + col] = f16_bits(p);
      }
    }

    __syncthreads();                  // B: sP visible; QK reads of sQ done
    if (ji + 1 < 64) stage_Q(j0+64);  // overlaps PV, drained at next barrier A

    // ---- PV: O[64 i x 32 c] for this wave's c-slab
    #pragma unroll
    for (int ks2=0; ks2<2; ks2++) {
      half8 aP[4];
      #pragma unroll
      for (int ig=0;ig<4;ig++)
        aP[ig] = ld_half8(&sP[ig*16 + col][ks2*32 + quad*8]);
      #pragma unroll
      for (int ct=0;ct<2;ct++)
        #pragma unroll
        for (int ig=0;ig<4;ig++)
          o[ig][ct] = __builtin_amdgcn_mfma_f32_16x16x32_f16(aP[ig], bF[ks2][ct], o[ig][ct], 0, 0, 0);
    }
  }

  // ---- final l: reduce 16 j-cols in-wave, combine halves via LDS
  #pragma unroll
  for (int r=0;r<4;r++) {
    float ss = lrun[r];
    ss += __shfl_xor(ss, 1, 64);
    ss += __shfl_xor(ss, 2, 64);
    ss += __shfl_xor(ss, 4, 64);
    ss += __shfl_xor(ss, 8, 64);
    lrun[r] = ss;
  }
  #pragma unroll
  for (int r=0;r<4;r++)
    if (col == 0) sL[wh][wq*16 + quad*4 + r] = lrun[r];
  __syncthreads();
  #pragma unroll
  for (int ig=0;ig<4;ig++) {
    int base = ig*16 + quad*4;
    f32x4 l0 = *(const f32x4*)&sL[0][base];
    f32x4 l1 = *(const f32x4*)&sL[1][base];
    f32x4 mv = *(const f32x4*)(m_n + i0 + base);
    f32x4 minv;
    #pragma unroll
    for (int r=0;r<4;r++) minv[r] = mv[r] / (l0[r] + l1[r]);
    #pragma unroll
    for (int ct=0;ct<2;ct++) {
      int c = w*32 + ct*16 + col;
      f32x4 v;
      #pragma unroll
      for (int r=0;r<4;r++) v[r] = o[ig][ct][r] * minv[r];
      *(f32x4*)(out + ((size_t)n*CF + c)*HWX + i0 + base) = v;
    }
  }
}

extern "C" void kernel_launch(void* const* d_in, const int* in_sizes, int n_in,
                              void* d_out, int out_size, void* d_ws, size_t ws_size,
                              hipStream_t stream) {
  const float* x    = (const float*)d_in[0];
  const float* mask = (const float*)d_in[1];
  const float* rw   = (const float*)d_in[2];
  const float* rg   = (const float*)d_in[3];
  const float* rb   = (const float*)d_in[4];
  const float* rm   = (const float*)d_in[5];
  const float* rv   = (const float*)d_in[6];
  const float* aw   = (const float*)d_in[7];
  const float* ag   = (const float*)d_in[8];
  const float* ab   = (const float*)d_in[9];
  const float* am   = (const float*)d_in[10];
  const float* av   = (const float*)d_in[11];
  float* out = (float*)d_out;
  char* ws = (char*)d_ws;
  unsigned short* wh = (unsigned short*)(ws + OFF_WH);
  float* bias = (float*)(ws + OFF_BIAS);
  unsigned short* feat = (unsigned short*)(ws + OFF_FEAT);
  unsigned short* q    = (unsigned short*)(ws + OFF_Q);
  float* normq = (float*)(ws + OFF_NORM);
  unsigned* Gmax = (unsigned*)(ws + OFF_G);

  hipLaunchKernelGGL(fold_bn_k, dim3(CT), dim3(CIN), 0, stream,
                     rw, rg, rb, rm, rv, aw, ag, ab, am, av, wh, bias, Gmax);
  hipLaunchKernelGGL(conv_k, dim3(512), dim3(256), 0, stream,
                     x, wh, bias, feat, q, normq, Gmax);
  hipLaunchKernelGGL(flash_k, dim3(512), dim3(512), 0, stream,
                     q, feat, mask, normq, Gmax, out);
}